// Round 6
// baseline (84.722 us; speedup 1.0000x reference)
//
#include <hip/hip_runtime.h>
#include <hip/hip_bf16.h>
#include <math.h>

// Router: logits = X @ W^T + b ; top-2 over 64 experts; softmax over the 2; rest 0.
// X: [32768,1024] f32, W: [64,1024] f32, b: [64] f32, Out: [32768,64] f32.
//
// MFMA path: exact bf16 hi/lo split, 3-term product (hh + hl + lh). Near-tie
// tokens (3rd logit within TAU of v2) recomputed exactly by rescue kernel.
//
// Round-6 change: latency-bound fix. Fully-unrolled K-loop (static indices ->
// registers, not scratch) with split prefetch depths: X (HBM, ~900cy) 6 steps
// ahead, W (L2-resident 256KB, ~200cy) 2 steps ahead. Round 5 was 2-deep for
// both -> MfmaUtil 6%, VALUBusy 10%, both pipes idle on vmcnt.
//
// A/B k-mapping: element j of lane l covers k = (l>>4)*8 + j, identical for A
// (in-register split) and B (pack_w), so the k-sum is permutation-safe.
// C/D layout (m89-verified): col = lane&15, row = (lane>>4)*4 + reg.
//
// Requires ws_size >= 512 KB (cnt @0, list @256, Whi @256K, Wlo @384K).

typedef __attribute__((ext_vector_type(8))) short bf16x8;
typedef __attribute__((ext_vector_type(4))) float f32x4;

#define TOKENS 32768
#define DDIM   1024
#define KSTEPS 32
#define XDEPTH 6
#define WDEPTH 2
#define TAU    1e-3f

#define WS_CNT_OFF   0
#define WS_LIST_OFF  256
#define WS_WHI_OFF   262144
#define WS_WLO_OFF   (262144 + 131072)

union FragU { bf16x8 v; unsigned int u[4]; };

__device__ inline unsigned int pk_bf16(float a, float b) {
    float2 f; f.x = a; f.y = b;
    __hip_bfloat162 h = __float22bfloat162_rn(f);
    union { __hip_bfloat162 h2; unsigned int u; } cv; cv.h2 = h;
    return cv.u;
}
__device__ inline float2 bf2f2(unsigned int u) {
    union { __hip_bfloat162 h2; unsigned int uu; } cv; cv.uu = u;
    return __bfloat1622float2(cv.h2);
}
__device__ inline void merge2(float& v1, int& i1, float& v2, int& i2,
                              float o1, int oi1, float o2, int oi2) {
    const bool b1 = (o1 > v1) || (o1 == v1 && oi1 < i1);
    if (b1) {
        const bool b2 = (v1 > o2) || (v1 == o2 && i1 < oi2);
        v2 = b2 ? v1 : o2;  i2 = b2 ? i1 : oi2;
        v1 = o1;            i1 = oi1;
    } else {
        const bool b2 = (o1 > v2) || (o1 == v2 && oi1 < i2);
        if (b2) { v2 = o1; i2 = oi1; }
    }
}

// ---- kernel 1: pack W into fragment-ordered bf16 hi/lo ----
__launch_bounds__(256)
__global__ void pack_w_kernel(const float* __restrict__ W,
                              unsigned int* __restrict__ Whi,
                              unsigned int* __restrict__ Wlo) {
    const int idx = blockIdx.x * 256 + threadIdx.x;     // 0..8191 = (s,n,l)
    const int l = idx & 63, n = (idx >> 6) & 3, s = idx >> 8;
    const int e  = n * 16 + (l & 15);
    const int k0 = s * 32 + (l >> 4) * 8;
    const float* p = W + e * DDIM + k0;
    const float4 a = *(const float4*)p;
    const float4 b = *(const float4*)(p + 4);
    const float f[8] = {a.x, a.y, a.z, a.w, b.x, b.y, b.z, b.w};
    unsigned int hu[4], lu[4];
    #pragma unroll
    for (int j = 0; j < 4; ++j) {
        const float x0 = f[2 * j], x1 = f[2 * j + 1];
        const unsigned int h = pk_bf16(x0, x1);
        const float2 hf = bf2f2(h);
        hu[j] = h;
        lu[j] = pk_bf16(x0 - hf.x, x1 - hf.y);
    }
    uint4 hv; hv.x = hu[0]; hv.y = hu[1]; hv.z = hu[2]; hv.w = hu[3];
    uint4 lv; lv.x = lu[0]; lv.y = lu[1]; lv.z = lu[2]; lv.w = lu[3];
    *(uint4*)(Whi + (size_t)idx * 4) = hv;
    *(uint4*)(Wlo + (size_t)idx * 4) = lv;
}

// ---- kernel 2: main MFMA router ----
__launch_bounds__(256, 2)
__global__ void router_mfma(const float* __restrict__ X,
                            const unsigned int* __restrict__ Whi,
                            const unsigned int* __restrict__ Wlo,
                            const float* __restrict__ Bv,
                            float* __restrict__ Out,
                            unsigned int* __restrict__ flagCnt,
                            int* __restrict__ flagList) {
    const int tid  = threadIdx.x;
    const int w    = tid >> 6;
    const int lane = tid & 63;
    const int rl   = lane & 15;       // A-row / B-col / C-col index
    const int kg   = lane >> 4;       // k-group
    const int tokBase = blockIdx.x * 64 + w * 16;

    const float* xp = X + (size_t)(tokBase + rl) * DDIM + kg * 8;
    const unsigned int* whp = Whi + (size_t)lane * 4;
    const unsigned int* wlp = Wlo + (size_t)lane * 4;

    f32x4 acc[4] = {f32x4{0,0,0,0}, f32x4{0,0,0,0}, f32x4{0,0,0,0}, f32x4{0,0,0,0}};

    // Fully-unrolled pipeline state: all indices compile-time -> registers.
    // Live ranges: X ~XDEPTH*8 regs, W ~WDEPTH*32 regs.
    float4 xa[KSTEPS], xb[KSTEPS];
    FragU bh[KSTEPS][4], bl[KSTEPS][4];

#define LDX(s) { const float* p_ = xp + (s) * 32; \
        xa[s] = *(const float4*)p_; xb[s] = *(const float4*)(p_ + 4); }
#define LDW(s) { \
        _Pragma("unroll") for (int n_ = 0; n_ < 4; ++n_) { \
            const size_t off_ = (size_t)((((s) * 4 + n_) * 64)) * 4; \
            *(uint4*)&bh[s][n_].u[0] = *(const uint4*)(whp + off_); \
            *(uint4*)&bl[s][n_].u[0] = *(const uint4*)(wlp + off_); } }
#define CM(s) { \
        FragU ah_, al_; \
        const float fx_[8] = {xa[s].x, xa[s].y, xa[s].z, xa[s].w, \
                              xb[s].x, xb[s].y, xb[s].z, xb[s].w}; \
        _Pragma("unroll") for (int j_ = 0; j_ < 4; ++j_) { \
            const unsigned int h_ = pk_bf16(fx_[2*j_], fx_[2*j_+1]); \
            const float2 hf_ = bf2f2(h_); \
            ah_.u[j_] = h_; \
            al_.u[j_] = pk_bf16(fx_[2*j_] - hf_.x, fx_[2*j_+1] - hf_.y); } \
        _Pragma("unroll") for (int n_ = 0; n_ < 4; ++n_) { \
            acc[n_] = __builtin_amdgcn_mfma_f32_16x16x32_bf16(ah_.v, bh[s][n_].v, acc[n_], 0, 0, 0); \
            acc[n_] = __builtin_amdgcn_mfma_f32_16x16x32_bf16(ah_.v, bl[s][n_].v, acc[n_], 0, 0, 0); \
            acc[n_] = __builtin_amdgcn_mfma_f32_16x16x32_bf16(al_.v, bh[s][n_].v, acc[n_], 0, 0, 0); } }

    // Prologue: fill the split-depth pipeline.
    #pragma unroll
    for (int s = 0; s < XDEPTH; ++s) LDX(s);
    #pragma unroll
    for (int s = 0; s < WDEPTH; ++s) LDW(s);

    // Fully-unrolled main loop: issue next loads, then consume current step.
    #pragma unroll
    for (int s = 0; s < KSTEPS; ++s) {
        if (s + XDEPTH < KSTEPS) LDX(s + XDEPTH);
        if (s + WDEPTH < KSTEPS) LDW(s + WDEPTH);
        CM(s);
    }
#undef LDX
#undef LDW
#undef CM

    // ---- epilogue: bias + per-token top-2 (16-lane butterfly) + write ----
    float bv[4];
    #pragma unroll
    for (int n = 0; n < 4; ++n) bv[n] = Bv[n * 16 + rl];

    #pragma unroll
    for (int r = 0; r < 4; ++r) {
        float v[4];
        #pragma unroll
        for (int n = 0; n < 4; ++n) v[n] = acc[n][r] + bv[n];

        // in-lane top-2 over this lane's 4 experts (e = n*16 + rl)
        float v1 = -INFINITY, v2 = -INFINITY;
        int i1 = 0x7fffffff, i2 = 0x7fffffff;
        #pragma unroll
        for (int n = 0; n < 4; ++n) {
            const float val = v[n];
            const int   e   = n * 16 + rl;
            if (val > v1 || (val == v1 && e < i1)) { v2 = v1; i2 = i1; v1 = val; i1 = e; }
            else if (val > v2 || (val == v2 && e < i2)) { v2 = val; i2 = e; }
        }
        // butterfly across the 16 lanes of this k-group (lex: value desc, idx asc)
        #pragma unroll
        for (int st = 1; st <= 8; st <<= 1) {
            const float o1 = __shfl_xor(v1, st); const int oi1 = __shfl_xor(i1, st);
            const float o2 = __shfl_xor(v2, st); const int oi2 = __shfl_xor(i2, st);
            merge2(v1, i1, v2, i2, o1, oi1, o2, oi2);
        }
        // near-tie flag: any 3rd logit within TAU of v2?
        int cnt = 0;
        #pragma unroll
        for (int n = 0; n < 4; ++n) cnt += (v[n] > v2 - TAU) ? 1 : 0;
        cnt += __shfl_xor(cnt, 1);
        cnt += __shfl_xor(cnt, 2);
        cnt += __shfl_xor(cnt, 4);
        cnt += __shfl_xor(cnt, 8);

        const int T = tokBase + kg * 4 + r;
        if (rl == 0 && cnt > 2) {
            const unsigned int pos = atomicAdd(flagCnt, 1u);
            if (pos < TOKENS) flagList[pos] = T;
        }
        const float ex = expf(v2 - v1);      // <= 1
        const float w1 = 1.f / (1.f + ex);
        const float w2 = ex * w1;
        const int e0 = rl * 4;
        float4 o;
        o.x = (e0 + 0 == i1) ? w1 : ((e0 + 0 == i2) ? w2 : 0.f);
        o.y = (e0 + 1 == i1) ? w1 : ((e0 + 1 == i2) ? w2 : 0.f);
        o.z = (e0 + 2 == i1) ? w1 : ((e0 + 2 == i2) ? w2 : 0.f);
        o.w = (e0 + 3 == i1) ? w1 : ((e0 + 3 == i2) ? w2 : 0.f);
        *(float4*)(Out + (size_t)T * 64 + e0) = o;
    }
}

// ---- kernel 3: exact fp32 rescue for near-tie tokens ----
__launch_bounds__(64)
__global__ void rescue_kernel(const float* __restrict__ X,
                              const float* __restrict__ W,
                              const float* __restrict__ Bv,
                              float* __restrict__ Out,
                              const unsigned int* __restrict__ flagCnt,
                              const int* __restrict__ flagList) {
    __shared__ float sx[DDIM];
    const int lane = threadIdx.x;
    unsigned int n = *flagCnt;
    if (n > TOKENS) n = TOKENS;
    for (unsigned int i = blockIdx.x; i < n; i += gridDim.x) {
        const int t = flagList[i];
        __syncthreads();
        #pragma unroll
        for (int k = 0; k < 4; ++k)
            ((float4*)sx)[lane + 64 * k] =
                ((const float4*)(X + (size_t)t * DDIM))[lane + 64 * k];
        __syncthreads();
        float acc = Bv[lane];
        const float* wr = W + (size_t)lane * DDIM;
        #pragma unroll 4
        for (int d = 0; d < DDIM; d += 4) {
            const float4 wv = *(const float4*)(wr + d);
            acc = fmaf(sx[d + 0], wv.x, acc);
            acc = fmaf(sx[d + 1], wv.y, acc);
            acc = fmaf(sx[d + 2], wv.z, acc);
            acc = fmaf(sx[d + 3], wv.w, acc);
        }
        float v1 = acc, v2 = -INFINITY;
        int i1 = lane, i2 = 0x7fffffff;
        #pragma unroll
        for (int st = 1; st <= 32; st <<= 1) {
            const float o1 = __shfl_xor(v1, st); const int oi1 = __shfl_xor(i1, st);
            const float o2 = __shfl_xor(v2, st); const int oi2 = __shfl_xor(i2, st);
            merge2(v1, i1, v2, i2, o1, oi1, o2, oi2);
        }
        const float ex = expf(v2 - v1);
        const float w1 = 1.f / (1.f + ex);
        const float w2 = ex * w1;
        Out[(size_t)t * 64 + lane] = (lane == i1) ? w1 : ((lane == i2) ? w2 : 0.f);
    }
}

extern "C" void kernel_launch(void* const* d_in, const int* in_sizes, int n_in,
                              void* d_out, int out_size, void* d_ws, size_t ws_size,
                              hipStream_t stream) {
    const float* X  = (const float*)d_in[0];   // [32768, 1024]
    const float* W  = (const float*)d_in[1];   // [64, 1024]
    const float* Bv = (const float*)d_in[2];   // [64]
    float* Out = (float*)d_out;                // [32768, 64]

    unsigned char* ws = (unsigned char*)d_ws;
    unsigned int* cnt  = (unsigned int*)(ws + WS_CNT_OFF);
    int*          list = (int*)(ws + WS_LIST_OFF);
    unsigned int* Whi  = (unsigned int*)(ws + WS_WHI_OFF);
    unsigned int* Wlo  = (unsigned int*)(ws + WS_WLO_OFF);

    hipMemsetAsync(cnt, 0, 4, stream);
    hipLaunchKernelGGL(pack_w_kernel, dim3(32), dim3(256), 0, stream, W, Whi, Wlo);
    hipLaunchKernelGGL(router_mfma, dim3(TOKENS / 64), dim3(256), 0, stream,
                       X, Whi, Wlo, Bv, Out, cnt, list);
    hipLaunchKernelGGL(rescue_kernel, dim3(512), dim3(64), 0, stream,
                       X, W, Bv, Out, cnt, list);
}